// Round 18
// baseline (5639.348 us; speedup 1.0000x reference)
//
#include <hip/hip_runtime.h>
#include <stdint.h>

// ---------------- constants ----------------
#define NB   2048          // batch
#define SEQ  17
#define DIM  512
#define NTOK (NB * SEQ)    // 34816 rows (= 272*128)
#define NPAT (NB * 16)     // 32768 rows (= 256*128)

typedef __bf16 v8bf __attribute__((ext_vector_type(8)));
typedef float  f32x4 __attribute__((ext_vector_type(4)));

typedef const __attribute__((address_space(1))) void GVoid;
typedef __attribute__((address_space(3))) void LVoid;

__device__ __forceinline__ uint16_t f2bf(float f) {
  uint32_t u = __float_as_uint(f);
  uint32_t r = u + 0x7FFFu + ((u >> 16) & 1u);
  return (uint16_t)(r >> 16);
}
__device__ __forceinline__ float bf2f(uint16_t h) {
  return __uint_as_float(((uint32_t)h) << 16);
}
__device__ __forceinline__ void load16_lds(const void* g, void* l) {
  __builtin_amdgcn_global_load_lds((GVoid*)g, (LVoid*)l, 16, 0, 0);
}

// shared epilogue (EPI semantics identical across gemm kernels)
template <int EPI>
__device__ __forceinline__ void epi_store(
    float v, int row, int col, uint16_t* outb, const float* pos, int ldo) {
  if (EPI == 0) {
    outb[(size_t)row * ldo + col] = f2bf(v);
  } else if (EPI == 1) {
    v = v > 0.f ? v : 0.1f * v;
    outb[(size_t)row * ldo + col] = f2bf(v);
  } else if (EPI == 2) {
    // tanh-form GELU (err vs erf <= ~1e-3, below bf16 rounding)
    float u = 1.5957691216057308f * (v + 0.044715f * v * v * v);
    v = v / (1.f + __expf(-u));
    outb[(size_t)row * ldo + col] = f2bf(v);
  } else if (EPI == 3) {
    size_t o = (size_t)row * ldo + col;
    outb[o] = f2bf(bf2f(outb[o]) + v);
  } else {
    int bb = row >> 4, ss = row & 15;
    outb[((size_t)bb * 17 + ss) * 512 + col] = f2bf(v + pos[ss * 512 + col]);
  }
}

// ---------------- weight transpose+cast: (K,N) f32 -> (N,K) bf16, multi-layer via z ----------
__global__ __launch_bounds__(256) void transpose_cast(
    const float* __restrict__ in, uint16_t* __restrict__ out, int K, int N,
    size_t in_ls, size_t out_ls) {
  const float* src = in + (size_t)blockIdx.z * in_ls;
  uint16_t* dst = out + (size_t)blockIdx.z * out_ls;
  __shared__ uint16_t t[64][65];
  int k0 = blockIdx.y * 64, n0 = blockIdx.x * 64;
  int tid = threadIdx.x;
  int c = tid & 63, r0 = tid >> 6;
#pragma unroll
  for (int i = 0; i < 16; i++) {
    int r = i * 4 + r0;
    t[c][r] = f2bf(src[(size_t)(k0 + r) * N + n0 + c]);
  }
  __syncthreads();
#pragma unroll
  for (int i = 0; i < 16; i++) {
    int rn = i * 4 + r0;
    dst[(size_t)(n0 + rn) * K + k0 + c] = t[rn][c];
  }
}

// ---------------- xpad: zero-padded image, bf16 [NB][3][48][48] ----------------
__global__ __launch_bounds__(256) void xpad_fill(
    const float* __restrict__ x, uint16_t* __restrict__ xp) {
  int idx = blockIdx.x * 256 + threadIdx.x;
  int c8 = idx % 6;
  int r = (idx / 6) % 48;
  int i = (idx / 288) % 3;
  int b = idx / 864;
  int col0 = c8 * 8;
  uint16_t v[8];
  const float* src = x + ((size_t)(b * 3 + i) * 32 + (r - 7)) * 32;
#pragma unroll
  for (int e = 0; e < 8; e++) {
    int col = col0 + e;
    float val = (r >= 7 && r < 39 && col >= 7 && col < 39) ? src[col - 7] : 0.f;
    v[e] = f2bf(val);
  }
  *(uint4*)&xp[(((size_t)b * 3 + i) * 48 + r) * 48 + col0] = *(const uint4*)v;
}

// ---------------- G: gathered conv kernel matrix, bf16 [1792][192] ----------------
__global__ __launch_bounds__(256) void build_G(
    const float* __restrict__ w, uint16_t* __restrict__ G) {
  int idx = blockIdx.x * 256 + threadIdx.x;
  if (idx >= 1792 * 192) return;
  int j = idx % 192, k = idx / 192;
  int o = j >> 6, ry = (j >> 3) & 7, rx = j & 7;
  int i = k / 576, rem = k - i * 576;
  int dy = rem / 24, dx = rem % 24;
  float val = 0.f;
  if (i < 3) {
    int ky = dy - ry, kx = dx - rx;
    if (ky >= 0 && ky < 16 && kx >= 0 && kx < 16)
      val = w[o * 768 + i * 256 + ky * 16 + kx];
  }
  G[idx] = f2bf(val);
}

// ---------------- effective bias ----------------
__global__ __launch_bounds__(256) void bias_eff_kernel(
    const float* __restrict__ h_b1, const float* __restrict__ cb,
    const uint16_t* __restrict__ h1w, float* __restrict__ be) {
  int d = blockIdx.x * 256 + threadIdx.x;
  if (d >= 512) return;
  float s = h_b1[d];
#pragma unroll
  for (int o = 0; o < 3; o++) {
    float so = 0.f;
    for (int j = 0; j < 64; j++) so += bf2f(h1w[(size_t)d * 192 + o * 64 + j]);
    s += cb[o] * so;
  }
  be[d] = s;
}

// ---------------- 128x128 GEMM, m97 structure (single-buffered) + chunk-XOR swizzle ----------
// 256 threads = 4 waves (2M x 2N), per-wave 64x64 C, BK=64, 32KB LDS -> 4 blocks/CU.
// VERIFIED BEST STRUCTURE. Guardrails: launch_bounds (256,4) exactly (R12 spill);
// B staged via LDS (R14); no vmcnt games (R8).
template <int EPI, int ASRC>
__global__ __launch_bounds__(256, 4) void gemm128(
    const uint16_t* __restrict__ A, const uint16_t* __restrict__ W,
    const float* __restrict__ bias, uint16_t* __restrict__ outb,
    float* __restrict__ outf, const float* __restrict__ pos,
    int M, int N, int K, int lda, int ldw, int ldo) {
  __shared__ uint16_t As[128 * 64];
  __shared__ uint16_t Bs[128 * 64];
  const int tid = threadIdx.x;
  const int w = tid >> 6, l = tid & 63;
  const int lr = l & 15, lk = l >> 4;
  const int wm = w >> 1, wn = w & 1;

  int flat = blockIdx.y * gridDim.x + blockIdx.x;
  int nwg = gridDim.x * gridDim.y;
  int q = nwg >> 3, r = nwg & 7;
  int xcd = flat & 7, idx = flat >> 3;
  int f2 = (xcd < r ? xcd * (q + 1) : r * (q + 1) + (xcd - r) * q) + idx;
  const int m0 = (f2 / gridDim.x) * 128, n0 = (f2 % gridDim.x) * 128;

  f32x4 acc[4][4];
#pragma unroll
  for (int i = 0; i < 4; i++)
#pragma unroll
    for (int j = 0; j < 4; j++) acc[i][j] = (f32x4){0.f, 0.f, 0.f, 0.f};

  const int gr8 = l >> 3;
  const int csw = ((l & 7) ^ gr8) * 8;

  size_t abase[4];
  if (ASRC == 1) {
#pragma unroll
    for (int i = 0; i < 4; i++) {
      int rr = m0 + w * 32 + i * 8 + gr8;
      int b = rr >> 4, patch = rr & 15;
      int py = patch >> 2, px = patch & 3;
      abase[i] = (size_t)b * 6912 + py * 384 + px * 8;
    }
  }

  const int nkt = K >> 6;
  for (int kt = 0; kt < nkt; kt++) {
    const uint16_t* Bb = W + (size_t)n0 * ldw + (size_t)kt * 64;
    if (ASRC == 0) {
      const uint16_t* Ab = A + (size_t)m0 * lda + (size_t)kt * 64;
#pragma unroll
      for (int i = 0; i < 4; i++) {
        load16_lds(Ab + (size_t)(w * 32 + i * 8 + gr8) * lda + csw, As + w * 2048 + i * 512);
        load16_lds(Bb + (size_t)(w * 32 + i * 8 + gr8) * ldw + csw, Bs + w * 2048 + i * 512);
      }
    } else {
      int c8 = kt * 8 + ((l & 7) ^ gr8);
      int ii = c8 / 72, rem = c8 - ii * 72;
      int dy = rem / 3, dx0 = (rem - dy * 3) * 8;
      size_t koff = (size_t)ii * 2304 + dy * 48 + dx0;
#pragma unroll
      for (int i = 0; i < 4; i++) {
        load16_lds(A + abase[i] + koff, As + w * 2048 + i * 512);
        load16_lds(Bb + (size_t)(w * 32 + i * 8 + gr8) * ldw + csw, Bs + w * 2048 + i * 512);
      }
    }
    __syncthreads();
    {
      const int xm = lr & 7;
#pragma unroll
      for (int kk = 0; kk < 64; kk += 32) {
        const int j = (kk >> 3) + lk;
        const int pc = (j ^ xm) << 3;
        v8bf a[4], b[4];
#pragma unroll
        for (int mi = 0; mi < 4; mi++)
          a[mi] = *(const v8bf*)&As[(wm * 64 + mi * 16 + lr) * 64 + pc];
#pragma unroll
        for (int ni = 0; ni < 4; ni++)
          b[ni] = *(const v8bf*)&Bs[(wn * 64 + ni * 16 + lr) * 64 + pc];
#pragma unroll
        for (int mi = 0; mi < 4; mi++)
#pragma unroll
          for (int ni = 0; ni < 4; ni++)
            acc[mi][ni] = __builtin_amdgcn_mfma_f32_16x16x32_bf16(a[mi], b[ni], acc[mi][ni], 0, 0, 0);
      }
    }
    __syncthreads();
  }

#pragma unroll
  for (int mi = 0; mi < 4; mi++) {
#pragma unroll
    for (int ni = 0; ni < 4; ni++) {
      int col = n0 + wn * 64 + ni * 16 + lr;
      float bv = bias ? bias[col] : 0.f;
#pragma unroll
      for (int q2 = 0; q2 < 4; q2++) {
        int row = m0 + wm * 64 + mi * 16 + lk * 4 + q2;
        epi_store<EPI>(acc[mi][ni][q2] + bv, row, col, outb, pos, ldo);
      }
    }
  }
}

// ---------------- 128x256 GEMM (wide-N): same sync structure & per-thread resources ----------
// 512 threads = 8 waves (2M x 4N), per-wave 64x64 C (acc[4][4] identical to gemm128),
// BK=64, LDS 48KB (A 16 + B 32) -> 2 blocks/CU at launch_bounds(512,4) [=4 waves/EU],
// VGPR cap 128 (no spill). For N>=1024 GEMMs only (qkv, mlp1): LDS bytes/FLOP -31%,
// B L2-refetch halves. Row-major A only (ASRC=0 semantics).
template <int EPI>
__global__ __launch_bounds__(512, 4) void gemmw(
    const uint16_t* __restrict__ A, const uint16_t* __restrict__ W,
    const float* __restrict__ bias, uint16_t* __restrict__ outb,
    const float* __restrict__ pos,
    int M, int N, int K, int lda, int ldw, int ldo) {
  __shared__ uint16_t As[128 * 64];   // 16 KB
  __shared__ uint16_t Bs[256 * 64];   // 32 KB
  const int tid = threadIdx.x;
  const int w = tid >> 6, l = tid & 63;
  const int lr = l & 15, lk = l >> 4;
  const int wm = w >> 2, wn = w & 3;

  int flat = blockIdx.y * gridDim.x + blockIdx.x;
  int nwg = gridDim.x * gridDim.y;
  int q = nwg >> 3, r = nwg & 7;
  int xcd = flat & 7, idx = flat >> 3;
  int f2 = (xcd < r ? xcd * (q + 1) : r * (q + 1) + (xcd - r) * q) + idx;
  const int m0 = (f2 / gridDim.x) * 128, n0 = (f2 % gridDim.x) * 256;

  f32x4 acc[4][4];
#pragma unroll
  for (int i = 0; i < 4; i++)
#pragma unroll
    for (int j = 0; j < 4; j++) acc[i][j] = (f32x4){0.f, 0.f, 0.f, 0.f};

  const int gr8 = l >> 3;
  const int csw = ((l & 7) ^ gr8) * 8;

  const int nkt = K >> 6;
  for (int kt = 0; kt < nkt; kt++) {
    const uint16_t* Ab = A + (size_t)m0 * lda + (size_t)kt * 64;
    const uint16_t* Bb = W + (size_t)n0 * ldw + (size_t)kt * 64;
    // A: 128 rows, wave w covers rows [w*16, w*16+16): 2 loads/lane
#pragma unroll
    for (int i = 0; i < 2; i++)
      load16_lds(Ab + (size_t)(w * 16 + i * 8 + gr8) * lda + csw, As + w * 1024 + i * 512);
    // B: 256 rows, wave w covers rows [w*32, w*32+32): 4 loads/lane
#pragma unroll
    for (int i = 0; i < 4; i++)
      load16_lds(Bb + (size_t)(w * 32 + i * 8 + gr8) * ldw + csw, Bs + w * 2048 + i * 512);
    __syncthreads();
    {
      const int xm = lr & 7;
#pragma unroll
      for (int kk = 0; kk < 64; kk += 32) {
        const int j = (kk >> 3) + lk;
        const int pc = (j ^ xm) << 3;
        v8bf a[4], b[4];
#pragma unroll
        for (int mi = 0; mi < 4; mi++)
          a[mi] = *(const v8bf*)&As[(wm * 64 + mi * 16 + lr) * 64 + pc];
#pragma unroll
        for (int ni = 0; ni < 4; ni++)
          b[ni] = *(const v8bf*)&Bs[(wn * 64 + ni * 16 + lr) * 64 + pc];
#pragma unroll
        for (int mi = 0; mi < 4; mi++)
#pragma unroll
          for (int ni = 0; ni < 4; ni++)
            acc[mi][ni] = __builtin_amdgcn_mfma_f32_16x16x32_bf16(a[mi], b[ni], acc[mi][ni], 0, 0, 0);
      }
    }
    __syncthreads();
  }

#pragma unroll
  for (int mi = 0; mi < 4; mi++) {
#pragma unroll
    for (int ni = 0; ni < 4; ni++) {
      int col = n0 + wn * 64 + ni * 16 + lr;
      float bv = bias ? bias[col] : 0.f;
#pragma unroll
      for (int q2 = 0; q2 < 4; q2++) {
        int row = m0 + wm * 64 + mi * 16 + lk * 4 + q2;
        epi_store<EPI>(acc[mi][ni][q2] + bv, row, col, outb, pos, ldo);
      }
    }
  }
}

// ---------------- LayerNorm: one wave per row, bf16 in (uint4 x8), bf16 out ----------
__global__ __launch_bounds__(256) void ln_kernel(
    const uint16_t* __restrict__ h, const float* __restrict__ s,
    const float* __restrict__ b, uint16_t* __restrict__ out) {
  int wid = threadIdx.x >> 6, l = threadIdx.x & 63;
  int row = blockIdx.x * 4 + wid;
  uint4 u = *(const uint4*)(h + (size_t)row * 512 + l * 8);
  const uint16_t* pu = (const uint16_t*)&u;
  float v[8];
#pragma unroll
  for (int i = 0; i < 8; i++) v[i] = bf2f(pu[i]);
  float sum = 0.f, sq = 0.f;
#pragma unroll
  for (int i = 0; i < 8; i++) { sum += v[i]; sq += v[i] * v[i]; }
#pragma unroll
  for (int off = 1; off < 64; off <<= 1) {
    sum += __shfl_xor(sum, off);
    sq += __shfl_xor(sq, off);
  }
  float mean = sum * (1.f / 512.f);
  float var = sq * (1.f / 512.f) - mean * mean;
  float rs = rsqrtf(var + 1e-5f);
  float4 s0 = *(const float4*)(s + l * 8);
  float4 s1 = *(const float4*)(s + l * 8 + 4);
  float4 b0 = *(const float4*)(b + l * 8);
  float4 b1 = *(const float4*)(b + l * 8 + 4);
  float sv[8] = {s0.x, s0.y, s0.z, s0.w, s1.x, s1.y, s1.z, s1.w};
  float bv[8] = {b0.x, b0.y, b0.z, b0.w, b1.x, b1.y, b1.z, b1.w};
  uint16_t pk[8];
#pragma unroll
  for (int i = 0; i < 8; i++) pk[i] = f2bf((v[i] - mean) * rs * sv[i] + bv[i]);
  *(uint4*)(out + (size_t)row * 512 + l * 8) = *(const uint4*)pk;
}

// ---------------- attention per (b,h): 64 threads, padded LDS + vectorized I/O ----------
__global__ __launch_bounds__(64) void attn_kernel(
    const uint16_t* __restrict__ qkv, uint16_t* __restrict__ o) {
  int bh = blockIdx.x;
  int b = bh >> 4, h = bh & 15;
  __shared__ float Q[17][33], Kk[17][33], V[17][33], P[17][18];
  int tid = threadIdx.x;
  const uint16_t* base = qkv + (size_t)b * SEQ * 1536 + h * 32;
  for (int idx = tid; idx < 204; idx += 64) {
    int mat = idx / 68, rem = idx % 68;
    int s = rem >> 2, c = rem & 3;
    uint4 u = *(const uint4*)(base + (size_t)s * 1536 + mat * 512 + c * 8);
    const uint16_t* pu = (const uint16_t*)&u;
    float* dst = (mat == 0 ? Q[s] : mat == 1 ? Kk[s] : V[s]) + c * 8;
#pragma unroll
    for (int e = 0; e < 8; e++) dst[e] = bf2f(pu[e]);
  }
  __syncthreads();
  for (int idx = tid; idx < 289; idx += 64) {
    int i = idx / 17, j = idx % 17;
    float acc = 0.f;
#pragma unroll
    for (int d = 0; d < 32; d++) acc += Q[i][d] * Kk[j][d];
    P[i][j] = acc * 0.17677669529663687f;
  }
  __syncthreads();
  if (tid < 17) {
    float m = -1e30f;
    for (int j = 0; j < 17; j++) m = fmaxf(m, P[tid][j]);
    float sum = 0.f;
    for (int j = 0; j < 17; j++) { float e = __expf(P[tid][j] - m); P[tid][j] = e; sum += e; }
    float inv = 1.f / sum;
    for (int j = 0; j < 17; j++) P[tid][j] *= inv;
  }
  __syncthreads();
  uint16_t* ob = o + (size_t)b * SEQ * 512 + h * 32;
  for (int idx = tid; idx < 68; idx += 64) {
    int s = idx >> 2, c = idx & 3;
    float acc[8] = {0, 0, 0, 0, 0, 0, 0, 0};
#pragma unroll
    for (int t = 0; t < 17; t++) {
      float p = P[s][t];
      const float* vr = &V[t][c * 8];
#pragma unroll
      for (int e = 0; e < 8; e++) acc[e] += p * vr[e];
    }
    uint16_t pk[8];
#pragma unroll
    for (int e = 0; e < 8; e++) pk[e] = f2bf(acc[e]);
    *(uint4*)(ob + (size_t)s * 512 + c * 8) = *(const uint4*)pk;
  }
}

// ---------------- cls token row fill (bf16 h) ----------------
__global__ void fill_cls(const float* __restrict__ cls_tok,
                         const float* __restrict__ pos, uint16_t* __restrict__ h) {
  int b = blockIdx.x, d = threadIdx.x;
  h[((size_t)b * SEQ + 16) * 512 + d] = f2bf(cls_tok[d] + pos[16 * 512 + d]);
}

// ---------------- final LN (row 0, bf16 h) + classifier ----------------
__global__ __launch_bounds__(64) void final_head(
    const uint16_t* __restrict__ h, const float* __restrict__ fs,
    const float* __restrict__ fb, const float* __restrict__ cw,
    const float* __restrict__ cb, float* __restrict__ out) {
  int b = blockIdx.x;
  const uint16_t* x = h + (size_t)b * SEQ * 512;
  int l = threadIdx.x;
  uint4 u = *(const uint4*)(x + l * 8);
  const uint16_t* pu = (const uint16_t*)&u;
  float v[8];
  float sum = 0.f, sq = 0.f;
#pragma unroll
  for (int i = 0; i < 8; i++) { v[i] = bf2f(pu[i]); sum += v[i]; sq += v[i] * v[i]; }
#pragma unroll
  for (int off = 1; off < 64; off <<= 1) { sum += __shfl_xor(sum, off); sq += __shfl_xor(sq, off); }
  float mean = sum * (1.f / 512.f);
  float var = sq * (1.f / 512.f) - mean * mean;
  float rs = rsqrtf(var + 1e-5f);
  __shared__ float n[512];
#pragma unroll
  for (int i = 0; i < 8; i++) n[l * 8 + i] = (v[i] - mean) * rs * fs[l * 8 + i] + fb[l * 8 + i];
  __syncthreads();
  if (l < 10) {
    float acc = cb[l];
    for (int d = 0; d < 512; d++) acc += n[d] * cw[d * 10 + l];
    out[(size_t)b * 10 + l] = acc;
  }
}

// ---------------- launch ----------------
extern "C" void kernel_launch(void* const* d_in, const int* in_sizes, int n_in,
                              void* d_out, int out_size, void* d_ws, size_t ws_size,
                              hipStream_t stream) {
  const float* x       = (const float*)d_in[0];
  const float* conv_w  = (const float*)d_in[1];
  const float* conv_b  = (const float*)d_in[2];
  const float* h_w1    = (const float*)d_in[3];
  const float* h_b1    = (const float*)d_in[4];
  const float* h_w2    = (const float*)d_in[5];
  const float* h_b2    = (const float*)d_in[6];
  const float* cls_tok = (const float*)d_in[7];
  const float* pos_emb = (const float*)d_in[8];
  const float* ln1_s   = (const float*)d_in[9];
  const float* ln1_b   = (const float*)d_in[10];
  const float* qkv_w   = (const float*)d_in[11];
  const float* qkv_b   = (const float*)d_in[12];
  const float* proj_w  = (const float*)d_in[13];
  const float* proj_b  = (const float*)d_in[14];
  const float* ln2_s   = (const float*)d_in[15];
  const float* ln2_b   = (const float*)d_in[16];
  const float* mlp_w1  = (const float*)d_in[17];
  const float* mlp_b1  = (const float*)d_in[18];
  const float* mlp_w2  = (const float*)d_in[19];
  const float* mlp_b2  = (const float*)d_in[20];
  const float* fin_s   = (const float*)d_in[21];
  const float* fin_b   = (const float*)d_in[22];
  const float* cls_w   = (const float*)d_in[23];
  const float* cls_b   = (const float*)d_in[24];

  size_t off = 0;
  char* wsb = (char*)d_ws;
  auto take = [&](size_t bytes) -> void* {
    void* p = wsb + off;
    off += (bytes + 255) & ~(size_t)255;
    return p;
  };
  uint16_t* h1w  = (uint16_t*)take((size_t)512 * 192 * 2);
  uint16_t* h2w  = (uint16_t*)take((size_t)512 * 512 * 2);
  uint16_t* h    = (uint16_t*)take((size_t)NTOK * 512 * 2);    //  35.7 MB (bf16 residual)
  uint16_t* nbuf = (uint16_t*)take((size_t)NTOK * 512 * 2);    //  35.7 MB
  uint16_t* big  = (uint16_t*)take((size_t)NTOK * 2048 * 2);   // 142.6 MB
  if (off > ws_size) return;
  size_t base_end = off;

  uint16_t* wqA = (uint16_t*)take((size_t)12 * 1536 * 512 * 2);
  uint16_t* wpA = (uint16_t*)take((size_t)12 * 512 * 512 * 2);
  uint16_t* w1A = (uint16_t*)take((size_t)12 * 2048 * 512 * 2);
  uint16_t* w2A = (uint16_t*)take((size_t)12 * 512 * 2048 * 2);
  bool all_fit = (off <= ws_size);
  uint16_t *wq = wqA, *wp = wpA, *w1 = w1A, *w2 = w2A;
  if (!all_fit) {
    off = base_end;
    wq = (uint16_t*)take((size_t)1536 * 512 * 2);
    wp = (uint16_t*)take((size_t)512 * 512 * 2);
    w1 = (uint16_t*)take((size_t)2048 * 512 * 2);
    w2 = (uint16_t*)take((size_t)512 * 2048 * 2);
    if (off > ws_size) return;
  }

  uint16_t* xpad = big;
  uint16_t* G    = (uint16_t*)((char*)big + 28311552);
  uint16_t* weff = (uint16_t*)((char*)big + 28311552 + 688128);
  float*    beff = (float*)((char*)big + 28311552 + 688128 + 1835008);
  uint16_t* hid1 = nbuf;

  dim3 blk(256), blkw(512);
  transpose_cast<<<dim3(8, 3), blk, 0, stream>>>(h_w1, h1w, 192, 512, 0, 0);
  transpose_cast<<<dim3(8, 8), blk, 0, stream>>>(h_w2, h2w, 512, 512, 0, 0);
  if (all_fit) {
    transpose_cast<<<dim3(24, 8, 12), blk, 0, stream>>>(qkv_w, wqA, 512, 1536,
                                                        (size_t)512 * 1536, (size_t)1536 * 512);
    transpose_cast<<<dim3(8, 8, 12), blk, 0, stream>>>(proj_w, wpA, 512, 512,
                                                       (size_t)512 * 512, (size_t)512 * 512);
    transpose_cast<<<dim3(32, 8, 12), blk, 0, stream>>>(mlp_w1, w1A, 512, 2048,
                                                        (size_t)512 * 2048, (size_t)2048 * 512);
    transpose_cast<<<dim3(8, 32, 12), blk, 0, stream>>>(mlp_w2, w2A, 2048, 512,
                                                        (size_t)2048 * 512, (size_t)512 * 2048);
  }

  // folded conv + patch-MLP
  xpad_fill<<<dim3(NB * 3 * 48 * 6 / 256), blk, 0, stream>>>(x, xpad);
  build_G<<<dim3((1792 * 192 + 255) / 256), blk, 0, stream>>>(conv_w, G);
  bias_eff_kernel<<<dim3(2), blk, 0, stream>>>(h_b1, conv_b, h1w, beff);
  gemm128<0, 0><<<dim3(14, 4), blk, 0, stream>>>(h1w, G, nullptr, weff, nullptr, nullptr,
                                                 512, 1792, 192, 192, 192, 1792);
  gemm128<1, 1><<<dim3(4, 256), blk, 0, stream>>>(xpad, weff, beff, hid1, nullptr, nullptr,
                                                  NPAT, 512, 1728, 0, 1792, 512);
  gemm128<4, 0><<<dim3(4, 256), blk, 0, stream>>>(hid1, h2w, h_b2, h, nullptr, pos_emb,
                                                  NPAT, 512, 512, 512, 512, 512);
  fill_cls<<<dim3(NB), dim3(512), 0, stream>>>(cls_tok, pos_emb, h);

  for (int l = 0; l < 12; l++) {
    uint16_t *wq_l, *wp_l, *w1_l, *w2_l;
    if (all_fit) {
      wq_l = wqA + (size_t)l * 1536 * 512;
      wp_l = wpA + (size_t)l * 512 * 512;
      w1_l = w1A + (size_t)l * 2048 * 512;
      w2_l = w2A + (size_t)l * 512 * 2048;
    } else {
      wq_l = wq; wp_l = wp; w1_l = w1; w2_l = w2;
      transpose_cast<<<dim3(24, 8), blk, 0, stream>>>(qkv_w + (size_t)l * 512 * 1536, wq, 512, 1536, 0, 0);
      transpose_cast<<<dim3(8, 8), blk, 0, stream>>>(proj_w + (size_t)l * 512 * 512, wp, 512, 512, 0, 0);
      transpose_cast<<<dim3(32, 8), blk, 0, stream>>>(mlp_w1 + (size_t)l * 512 * 2048, w1, 512, 2048, 0, 0);
      transpose_cast<<<dim3(8, 32), blk, 0, stream>>>(mlp_w2 + (size_t)l * 2048 * 512, w2, 2048, 512, 0, 0);
    }

    ln_kernel<<<dim3(NTOK / 4), blk, 0, stream>>>(h, ln1_s + l * 512, ln1_b + l * 512, nbuf);
    gemmw<0><<<dim3(6, 272), blkw, 0, stream>>>(nbuf, wq_l, qkv_b + l * 1536,
                                                big, nullptr,
                                                NTOK, 1536, 512, 512, 512, 1536);
    attn_kernel<<<dim3(NB * 16), dim3(64), 0, stream>>>(big, nbuf);
    gemm128<3, 0><<<dim3(4, 272), blk, 0, stream>>>(nbuf, wp_l, proj_b + l * 512,
                                                    h, nullptr, nullptr,
                                                    NTOK, 512, 512, 512, 512, 512);
    ln_kernel<<<dim3(NTOK / 4), blk, 0, stream>>>(h, ln2_s + l * 512, ln2_b + l * 512, nbuf);
    gemmw<2><<<dim3(8, 272), blkw, 0, stream>>>(nbuf, w1_l, mlp_b1 + l * 2048,
                                                big, nullptr,
                                                NTOK, 2048, 512, 512, 512, 2048);
    gemm128<3, 0><<<dim3(4, 272), blk, 0, stream>>>(big, w2_l, mlp_b2 + l * 512,
                                                    h, nullptr, nullptr,
                                                    NTOK, 512, 2048, 2048, 2048, 512);
  }
  final_head<<<dim3(NB), dim3(64), 0, stream>>>(h, fin_s, fin_b, cls_w, cls_b, (float*)d_out);
}

// Round 19
// 5464.006 us; speedup vs baseline: 1.0321x; 1.0321x over previous
//
#include <hip/hip_runtime.h>
#include <stdint.h>

// ---------------- constants ----------------
#define NB   2048          // batch
#define SEQ  17
#define DIM  512
#define NTOK (NB * SEQ)    // 34816 rows (= 272*128)
#define NPAT (NB * 16)     // 32768 rows (= 256*128)

typedef __bf16 v8bf __attribute__((ext_vector_type(8)));
typedef float  f32x4 __attribute__((ext_vector_type(4)));

typedef const __attribute__((address_space(1))) void GVoid;
typedef __attribute__((address_space(3))) void LVoid;

__device__ __forceinline__ uint16_t f2bf(float f) {
  uint32_t u = __float_as_uint(f);
  uint32_t r = u + 0x7FFFu + ((u >> 16) & 1u);
  return (uint16_t)(r >> 16);
}
__device__ __forceinline__ float bf2f(uint16_t h) {
  return __uint_as_float(((uint32_t)h) << 16);
}
__device__ __forceinline__ void load16_lds(const void* g, void* l) {
  __builtin_amdgcn_global_load_lds((GVoid*)g, (LVoid*)l, 16, 0, 0);
}

// ---------------- weight transpose+cast: (K,N) f32 -> (N,K) bf16, multi-layer via z ----------
__global__ __launch_bounds__(256) void transpose_cast(
    const float* __restrict__ in, uint16_t* __restrict__ out, int K, int N,
    size_t in_ls, size_t out_ls) {
  const float* src = in + (size_t)blockIdx.z * in_ls;
  uint16_t* dst = out + (size_t)blockIdx.z * out_ls;
  __shared__ uint16_t t[64][65];
  int k0 = blockIdx.y * 64, n0 = blockIdx.x * 64;
  int tid = threadIdx.x;
  int c = tid & 63, r0 = tid >> 6;
#pragma unroll
  for (int i = 0; i < 16; i++) {
    int r = i * 4 + r0;
    t[c][r] = f2bf(src[(size_t)(k0 + r) * N + n0 + c]);
  }
  __syncthreads();
#pragma unroll
  for (int i = 0; i < 16; i++) {
    int rn = i * 4 + r0;
    dst[(size_t)(n0 + rn) * K + k0 + c] = t[rn][c];
  }
}

// ---------------- xpad: zero-padded image, bf16 [NB][3][48][48] ----------------
__global__ __launch_bounds__(256) void xpad_fill(
    const float* __restrict__ x, uint16_t* __restrict__ xp) {
  int idx = blockIdx.x * 256 + threadIdx.x;
  int c8 = idx % 6;
  int r = (idx / 6) % 48;
  int i = (idx / 288) % 3;
  int b = idx / 864;
  int col0 = c8 * 8;
  uint16_t v[8];
  const float* src = x + ((size_t)(b * 3 + i) * 32 + (r - 7)) * 32;
#pragma unroll
  for (int e = 0; e < 8; e++) {
    int col = col0 + e;
    float val = (r >= 7 && r < 39 && col >= 7 && col < 39) ? src[col - 7] : 0.f;
    v[e] = f2bf(val);
  }
  *(uint4*)&xp[(((size_t)b * 3 + i) * 48 + r) * 48 + col0] = *(const uint4*)v;
}

// ---------------- G: gathered conv kernel matrix, bf16 [1792][192] ----------------
__global__ __launch_bounds__(256) void build_G(
    const float* __restrict__ w, uint16_t* __restrict__ G) {
  int idx = blockIdx.x * 256 + threadIdx.x;
  if (idx >= 1792 * 192) return;
  int j = idx % 192, k = idx / 192;
  int o = j >> 6, ry = (j >> 3) & 7, rx = j & 7;
  int i = k / 576, rem = k - i * 576;
  int dy = rem / 24, dx = rem % 24;
  float val = 0.f;
  if (i < 3) {
    int ky = dy - ry, kx = dx - rx;
    if (ky >= 0 && ky < 16 && kx >= 0 && kx < 16)
      val = w[o * 768 + i * 256 + ky * 16 + kx];
  }
  G[idx] = f2bf(val);
}

// ---------------- effective bias ----------------
__global__ __launch_bounds__(256) void bias_eff_kernel(
    const float* __restrict__ h_b1, const float* __restrict__ cb,
    const uint16_t* __restrict__ h1w, float* __restrict__ be) {
  int d = blockIdx.x * 256 + threadIdx.x;
  if (d >= 512) return;
  float s = h_b1[d];
#pragma unroll
  for (int o = 0; o < 3; o++) {
    float so = 0.f;
    for (int j = 0; j < 64; j++) so += bf2f(h1w[(size_t)d * 192 + o * 64 + j]);
    s += cb[o] * so;
  }
  be[d] = s;
}

// ---------------- 128x128 GEMM, m97 structure (single-buffered) + chunk-XOR swizzle ----------
// 256 threads = 4 waves (2M x 2N), per-wave 64x64 C, BK=64, 32KB LDS -> 4 blocks/CU.
// VERIFIED BEST (R16: 5.470 ms total). Guardrails from this session:
//  - launch_bounds exactly (256,4): 5 forces VGPR<64 -> acc spills (R12, 2.2x slower)
//  - B staged via LDS, not direct-from-L2 (R14: latency-bound, 1.9x slower)
//  - single-buffered + __syncthreads, no vmcnt games (R5/R7/R8 neutral-to-worse)
//  - 128x128 tile, not 256-wide variants (R4/R18 regressions)
// EPI: 0=bias->bf16  1=bias+leaky->bf16  2=bias+gelu(erf)->bf16
//      3=bf16 residual RMW  4=patch scatter + pos_emb -> bf16
// ASRC: 0 = row-major A (stride lda); 1 = xpad patch windows (K=1728)
template <int EPI, int ASRC>
__global__ __launch_bounds__(256, 4) void gemm128(
    const uint16_t* __restrict__ A, const uint16_t* __restrict__ W,
    const float* __restrict__ bias, uint16_t* __restrict__ outb,
    float* __restrict__ outf, const float* __restrict__ pos,
    int M, int N, int K, int lda, int ldw, int ldo) {
  __shared__ uint16_t As[128 * 64];
  __shared__ uint16_t Bs[128 * 64];
  const int tid = threadIdx.x;
  const int w = tid >> 6, l = tid & 63;
  const int lr = l & 15, lk = l >> 4;
  const int wm = w >> 1, wn = w & 1;

  // bijective XCD-chunked swizzle (m204)
  int flat = blockIdx.y * gridDim.x + blockIdx.x;
  int nwg = gridDim.x * gridDim.y;
  int q = nwg >> 3, r = nwg & 7;
  int xcd = flat & 7, idx = flat >> 3;
  int f2 = (xcd < r ? xcd * (q + 1) : r * (q + 1) + (xcd - r) * q) + idx;
  const int m0 = (f2 / gridDim.x) * 128, n0 = (f2 % gridDim.x) * 128;

  f32x4 acc[4][4];
#pragma unroll
  for (int i = 0; i < 4; i++)
#pragma unroll
    for (int j = 0; j < 4; j++) acc[i][j] = (f32x4){0.f, 0.f, 0.f, 0.f};

  const int gr8 = l >> 3;                    // row within 8-row group
  const int csw = ((l & 7) ^ gr8) * 8;       // swizzled source element col

  size_t abase[4];
  if (ASRC == 1) {
#pragma unroll
    for (int i = 0; i < 4; i++) {
      int rr = m0 + w * 32 + i * 8 + gr8;
      int b = rr >> 4, patch = rr & 15;
      int py = patch >> 2, px = patch & 3;
      abase[i] = (size_t)b * 6912 + py * 384 + px * 8;
    }
  }

  const int nkt = K >> 6;
  for (int kt = 0; kt < nkt; kt++) {
    const uint16_t* Bb = W + (size_t)n0 * ldw + (size_t)kt * 64;
    if (ASRC == 0) {
      const uint16_t* Ab = A + (size_t)m0 * lda + (size_t)kt * 64;
#pragma unroll
      for (int i = 0; i < 4; i++) {
        load16_lds(Ab + (size_t)(w * 32 + i * 8 + gr8) * lda + csw, As + w * 2048 + i * 512);
        load16_lds(Bb + (size_t)(w * 32 + i * 8 + gr8) * ldw + csw, Bs + w * 2048 + i * 512);
      }
    } else {
      int c8 = kt * 8 + ((l & 7) ^ gr8);
      int ii = c8 / 72, rem = c8 - ii * 72;
      int dy = rem / 3, dx0 = (rem - dy * 3) * 8;
      size_t koff = (size_t)ii * 2304 + dy * 48 + dx0;
#pragma unroll
      for (int i = 0; i < 4; i++) {
        load16_lds(A + abase[i] + koff, As + w * 2048 + i * 512);
        load16_lds(Bb + (size_t)(w * 32 + i * 8 + gr8) * ldw + csw, Bs + w * 2048 + i * 512);
      }
    }
    __syncthreads();
    {
      const int xm = lr & 7;
#pragma unroll
      for (int kk = 0; kk < 64; kk += 32) {
        const int j = (kk >> 3) + lk;          // logical chunk 0..7
        const int pc = (j ^ xm) << 3;          // physical element offset
        v8bf a[4], b[4];
#pragma unroll
        for (int mi = 0; mi < 4; mi++)
          a[mi] = *(const v8bf*)&As[(wm * 64 + mi * 16 + lr) * 64 + pc];
#pragma unroll
        for (int ni = 0; ni < 4; ni++)
          b[ni] = *(const v8bf*)&Bs[(wn * 64 + ni * 16 + lr) * 64 + pc];
#pragma unroll
        for (int mi = 0; mi < 4; mi++)
#pragma unroll
          for (int ni = 0; ni < 4; ni++)
            acc[mi][ni] = __builtin_amdgcn_mfma_f32_16x16x32_bf16(a[mi], b[ni], acc[mi][ni], 0, 0, 0);
      }
    }
    __syncthreads();
  }

#pragma unroll
  for (int mi = 0; mi < 4; mi++) {
#pragma unroll
    for (int ni = 0; ni < 4; ni++) {
      int col = n0 + wn * 64 + ni * 16 + lr;
      float bv = bias ? bias[col] : 0.f;
#pragma unroll
      for (int q2 = 0; q2 < 4; q2++) {
        int row = m0 + wm * 64 + mi * 16 + lk * 4 + q2;
        float v = acc[mi][ni][q2] + bv;
        if (EPI == 0) {
          outb[(size_t)row * ldo + col] = f2bf(v);
        } else if (EPI == 1) {
          v = v > 0.f ? v : 0.1f * v;
          outb[(size_t)row * ldo + col] = f2bf(v);
        } else if (EPI == 2) {
          v = 0.5f * v * (1.f + erff(v * 0.70710678118654752f));
          outb[(size_t)row * ldo + col] = f2bf(v);
        } else if (EPI == 3) {
          size_t o = (size_t)row * ldo + col;
          outb[o] = f2bf(bf2f(outb[o]) + v);
        } else {
          int bb = row >> 4, ss = row & 15;
          outb[((size_t)bb * 17 + ss) * 512 + col] = f2bf(v + pos[ss * 512 + col]);
        }
      }
    }
  }
}

// ---------------- LayerNorm: one wave per row, bf16 in (uint4 x8), bf16 out ----------
__global__ __launch_bounds__(256) void ln_kernel(
    const uint16_t* __restrict__ h, const float* __restrict__ s,
    const float* __restrict__ b, uint16_t* __restrict__ out) {
  int wid = threadIdx.x >> 6, l = threadIdx.x & 63;
  int row = blockIdx.x * 4 + wid;
  uint4 u = *(const uint4*)(h + (size_t)row * 512 + l * 8);
  const uint16_t* pu = (const uint16_t*)&u;
  float v[8];
#pragma unroll
  for (int i = 0; i < 8; i++) v[i] = bf2f(pu[i]);
  float sum = 0.f, sq = 0.f;
#pragma unroll
  for (int i = 0; i < 8; i++) { sum += v[i]; sq += v[i] * v[i]; }
#pragma unroll
  for (int off = 1; off < 64; off <<= 1) {
    sum += __shfl_xor(sum, off);
    sq += __shfl_xor(sq, off);
  }
  float mean = sum * (1.f / 512.f);
  float var = sq * (1.f / 512.f) - mean * mean;
  float rs = rsqrtf(var + 1e-5f);
  float4 s0 = *(const float4*)(s + l * 8);
  float4 s1 = *(const float4*)(s + l * 8 + 4);
  float4 b0 = *(const float4*)(b + l * 8);
  float4 b1 = *(const float4*)(b + l * 8 + 4);
  float sv[8] = {s0.x, s0.y, s0.z, s0.w, s1.x, s1.y, s1.z, s1.w};
  float bv[8] = {b0.x, b0.y, b0.z, b0.w, b1.x, b1.y, b1.z, b1.w};
  uint16_t pk[8];
#pragma unroll
  for (int i = 0; i < 8; i++) pk[i] = f2bf((v[i] - mean) * rs * sv[i] + bv[i]);
  *(uint4*)(out + (size_t)row * 512 + l * 8) = *(const uint4*)pk;
}

// ---------------- attention per (b,h): 64 threads, padded LDS + vectorized I/O ----------
__global__ __launch_bounds__(64) void attn_kernel(
    const uint16_t* __restrict__ qkv, uint16_t* __restrict__ o) {
  int bh = blockIdx.x;
  int b = bh >> 4, h = bh & 15;
  __shared__ float Q[17][33], Kk[17][33], V[17][33], P[17][18];
  int tid = threadIdx.x;
  const uint16_t* base = qkv + (size_t)b * SEQ * 1536 + h * 32;
  for (int idx = tid; idx < 204; idx += 64) {
    int mat = idx / 68, rem = idx % 68;
    int s = rem >> 2, c = rem & 3;
    uint4 u = *(const uint4*)(base + (size_t)s * 1536 + mat * 512 + c * 8);
    const uint16_t* pu = (const uint16_t*)&u;
    float* dst = (mat == 0 ? Q[s] : mat == 1 ? Kk[s] : V[s]) + c * 8;
#pragma unroll
    for (int e = 0; e < 8; e++) dst[e] = bf2f(pu[e]);
  }
  __syncthreads();
  for (int idx = tid; idx < 289; idx += 64) {
    int i = idx / 17, j = idx % 17;
    float acc = 0.f;
#pragma unroll
    for (int d = 0; d < 32; d++) acc += Q[i][d] * Kk[j][d];
    P[i][j] = acc * 0.17677669529663687f;
  }
  __syncthreads();
  if (tid < 17) {
    float m = -1e30f;
    for (int j = 0; j < 17; j++) m = fmaxf(m, P[tid][j]);
    float sum = 0.f;
    for (int j = 0; j < 17; j++) { float e = __expf(P[tid][j] - m); P[tid][j] = e; sum += e; }
    float inv = 1.f / sum;
    for (int j = 0; j < 17; j++) P[tid][j] *= inv;
  }
  __syncthreads();
  uint16_t* ob = o + (size_t)b * SEQ * 512 + h * 32;
  for (int idx = tid; idx < 68; idx += 64) {
    int s = idx >> 2, c = idx & 3;
    float acc[8] = {0, 0, 0, 0, 0, 0, 0, 0};
#pragma unroll
    for (int t = 0; t < 17; t++) {
      float p = P[s][t];
      const float* vr = &V[t][c * 8];
#pragma unroll
      for (int e = 0; e < 8; e++) acc[e] += p * vr[e];
    }
    uint16_t pk[8];
#pragma unroll
    for (int e = 0; e < 8; e++) pk[e] = f2bf(acc[e]);
    *(uint4*)(ob + (size_t)s * 512 + c * 8) = *(const uint4*)pk;
  }
}

// ---------------- cls token row fill (bf16 h) ----------------
__global__ void fill_cls(const float* __restrict__ cls_tok,
                         const float* __restrict__ pos, uint16_t* __restrict__ h) {
  int b = blockIdx.x, d = threadIdx.x;
  h[((size_t)b * SEQ + 16) * 512 + d] = f2bf(cls_tok[d] + pos[16 * 512 + d]);
}

// ---------------- final LN (row 0, bf16 h) + classifier ----------------
__global__ __launch_bounds__(64) void final_head(
    const uint16_t* __restrict__ h, const float* __restrict__ fs,
    const float* __restrict__ fb, const float* __restrict__ cw,
    const float* __restrict__ cb, float* __restrict__ out) {
  int b = blockIdx.x;
  const uint16_t* x = h + (size_t)b * SEQ * 512;   // row s=0
  int l = threadIdx.x;
  uint4 u = *(const uint4*)(x + l * 8);
  const uint16_t* pu = (const uint16_t*)&u;
  float v[8];
  float sum = 0.f, sq = 0.f;
#pragma unroll
  for (int i = 0; i < 8; i++) { v[i] = bf2f(pu[i]); sum += v[i]; sq += v[i] * v[i]; }
#pragma unroll
  for (int off = 1; off < 64; off <<= 1) { sum += __shfl_xor(sum, off); sq += __shfl_xor(sq, off); }
  float mean = sum * (1.f / 512.f);
  float var = sq * (1.f / 512.f) - mean * mean;
  float rs = rsqrtf(var + 1e-5f);
  __shared__ float n[512];
#pragma unroll
  for (int i = 0; i < 8; i++) n[l * 8 + i] = (v[i] - mean) * rs * fs[l * 8 + i] + fb[l * 8 + i];
  __syncthreads();
  if (l < 10) {
    float acc = cb[l];
    for (int d = 0; d < 512; d++) acc += n[d] * cw[d * 10 + l];
    out[(size_t)b * 10 + l] = acc;
  }
}

// ---------------- launch ----------------
extern "C" void kernel_launch(void* const* d_in, const int* in_sizes, int n_in,
                              void* d_out, int out_size, void* d_ws, size_t ws_size,
                              hipStream_t stream) {
  const float* x       = (const float*)d_in[0];
  const float* conv_w  = (const float*)d_in[1];
  const float* conv_b  = (const float*)d_in[2];
  const float* h_w1    = (const float*)d_in[3];
  const float* h_b1    = (const float*)d_in[4];
  const float* h_w2    = (const float*)d_in[5];
  const float* h_b2    = (const float*)d_in[6];
  const float* cls_tok = (const float*)d_in[7];
  const float* pos_emb = (const float*)d_in[8];
  const float* ln1_s   = (const float*)d_in[9];
  const float* ln1_b   = (const float*)d_in[10];
  const float* qkv_w   = (const float*)d_in[11];
  const float* qkv_b   = (const float*)d_in[12];
  const float* proj_w  = (const float*)d_in[13];
  const float* proj_b  = (const float*)d_in[14];
  const float* ln2_s   = (const float*)d_in[15];
  const float* ln2_b   = (const float*)d_in[16];
  const float* mlp_w1  = (const float*)d_in[17];
  const float* mlp_b1  = (const float*)d_in[18];
  const float* mlp_w2  = (const float*)d_in[19];
  const float* mlp_b2  = (const float*)d_in[20];
  const float* fin_s   = (const float*)d_in[21];
  const float* fin_b   = (const float*)d_in[22];
  const float* cls_w   = (const float*)d_in[23];
  const float* cls_b   = (const float*)d_in[24];

  size_t off = 0;
  char* wsb = (char*)d_ws;
  auto take = [&](size_t bytes) -> void* {
    void* p = wsb + off;
    off += (bytes + 255) & ~(size_t)255;
    return p;
  };
  uint16_t* h1w  = (uint16_t*)take((size_t)512 * 192 * 2);
  uint16_t* h2w  = (uint16_t*)take((size_t)512 * 512 * 2);
  uint16_t* h    = (uint16_t*)take((size_t)NTOK * 512 * 2);    //  35.7 MB (bf16 residual)
  uint16_t* nbuf = (uint16_t*)take((size_t)NTOK * 512 * 2);    //  35.7 MB
  uint16_t* big  = (uint16_t*)take((size_t)NTOK * 2048 * 2);   // 142.6 MB
  if (off > ws_size) return;
  size_t base_end = off;

  // try all-layers weight buffers (75.6 MB); fall back to rotating per-layer
  uint16_t* wqA = (uint16_t*)take((size_t)12 * 1536 * 512 * 2);
  uint16_t* wpA = (uint16_t*)take((size_t)12 * 512 * 512 * 2);
  uint16_t* w1A = (uint16_t*)take((size_t)12 * 2048 * 512 * 2);
  uint16_t* w2A = (uint16_t*)take((size_t)12 * 512 * 2048 * 2);
  bool all_fit = (off <= ws_size);
  uint16_t *wq = wqA, *wp = wpA, *w1 = w1A, *w2 = w2A;   // rotating fallbacks
  if (!all_fit) {
    off = base_end;
    wq = (uint16_t*)take((size_t)1536 * 512 * 2);
    wp = (uint16_t*)take((size_t)512 * 512 * 2);
    w1 = (uint16_t*)take((size_t)2048 * 512 * 2);
    w2 = (uint16_t*)take((size_t)512 * 2048 * 2);
    if (off > ws_size) return;
  }

  uint16_t* xpad = big;                                        // 28,311,552 B
  uint16_t* G    = (uint16_t*)((char*)big + 28311552);         //    688,128 B
  uint16_t* weff = (uint16_t*)((char*)big + 28311552 + 688128);// 1,835,008 B
  float*    beff = (float*)((char*)big + 28311552 + 688128 + 1835008);
  uint16_t* hid1 = nbuf;

  dim3 blk(256);
  transpose_cast<<<dim3(8, 3), blk, 0, stream>>>(h_w1, h1w, 192, 512, 0, 0);
  transpose_cast<<<dim3(8, 8), blk, 0, stream>>>(h_w2, h2w, 512, 512, 0, 0);
  if (all_fit) {
    transpose_cast<<<dim3(24, 8, 12), blk, 0, stream>>>(qkv_w, wqA, 512, 1536,
                                                        (size_t)512 * 1536, (size_t)1536 * 512);
    transpose_cast<<<dim3(8, 8, 12), blk, 0, stream>>>(proj_w, wpA, 512, 512,
                                                       (size_t)512 * 512, (size_t)512 * 512);
    transpose_cast<<<dim3(32, 8, 12), blk, 0, stream>>>(mlp_w1, w1A, 512, 2048,
                                                        (size_t)512 * 2048, (size_t)2048 * 512);
    transpose_cast<<<dim3(8, 32, 12), blk, 0, stream>>>(mlp_w2, w2A, 2048, 512,
                                                        (size_t)2048 * 512, (size_t)512 * 2048);
  }

  // folded conv + patch-MLP
  xpad_fill<<<dim3(NB * 3 * 48 * 6 / 256), blk, 0, stream>>>(x, xpad);
  build_G<<<dim3((1792 * 192 + 255) / 256), blk, 0, stream>>>(conv_w, G);
  bias_eff_kernel<<<dim3(2), blk, 0, stream>>>(h_b1, conv_b, h1w, beff);
  gemm128<0, 0><<<dim3(14, 4), blk, 0, stream>>>(h1w, G, nullptr, weff, nullptr, nullptr,
                                                 512, 1792, 192, 192, 192, 1792);
  gemm128<1, 1><<<dim3(4, 256), blk, 0, stream>>>(xpad, weff, beff, hid1, nullptr, nullptr,
                                                  NPAT, 512, 1728, 0, 1792, 512);
  gemm128<4, 0><<<dim3(4, 256), blk, 0, stream>>>(hid1, h2w, h_b2, h, nullptr, pos_emb,
                                                  NPAT, 512, 512, 512, 512, 512);
  fill_cls<<<dim3(NB), dim3(512), 0, stream>>>(cls_tok, pos_emb, h);

  for (int l = 0; l < 12; l++) {
    uint16_t *wq_l, *wp_l, *w1_l, *w2_l;
    if (all_fit) {
      wq_l = wqA + (size_t)l * 1536 * 512;
      wp_l = wpA + (size_t)l * 512 * 512;
      w1_l = w1A + (size_t)l * 2048 * 512;
      w2_l = w2A + (size_t)l * 512 * 2048;
    } else {
      wq_l = wq; wp_l = wp; w1_l = w1; w2_l = w2;
      transpose_cast<<<dim3(24, 8), blk, 0, stream>>>(qkv_w + (size_t)l * 512 * 1536, wq, 512, 1536, 0, 0);
      transpose_cast<<<dim3(8, 8), blk, 0, stream>>>(proj_w + (size_t)l * 512 * 512, wp, 512, 512, 0, 0);
      transpose_cast<<<dim3(32, 8), blk, 0, stream>>>(mlp_w1 + (size_t)l * 512 * 2048, w1, 512, 2048, 0, 0);
      transpose_cast<<<dim3(8, 32), blk, 0, stream>>>(mlp_w2 + (size_t)l * 2048 * 512, w2, 2048, 512, 0, 0);
    }

    ln_kernel<<<dim3(NTOK / 4), blk, 0, stream>>>(h, ln1_s + l * 512, ln1_b + l * 512, nbuf);
    gemm128<0, 0><<<dim3(12, 272), blk, 0, stream>>>(nbuf, wq_l, qkv_b + l * 1536,
                                                     big, nullptr, nullptr,
                                                     NTOK, 1536, 512, 512, 512, 1536);
    attn_kernel<<<dim3(NB * 16), dim3(64), 0, stream>>>(big, nbuf);
    gemm128<3, 0><<<dim3(4, 272), blk, 0, stream>>>(nbuf, wp_l, proj_b + l * 512,
                                                    h, nullptr, nullptr,
                                                    NTOK, 512, 512, 512, 512, 512);
    ln_kernel<<<dim3(NTOK / 4), blk, 0, stream>>>(h, ln2_s + l * 512, ln2_b + l * 512, nbuf);
    gemm128<2, 0><<<dim3(16, 272), blk, 0, stream>>>(nbuf, w1_l, mlp_b1 + l * 2048,
                                                     big, nullptr, nullptr,
                                                     NTOK, 2048, 512, 512, 512, 2048);
    gemm128<3, 0><<<dim3(4, 272), blk, 0, stream>>>(big, w2_l, mlp_b2 + l * 512,
                                                    h, nullptr, nullptr,
                                                    NTOK, 512, 2048, 2048, 2048, 512);
  }
  final_head<<<dim3(NB), dim3(64), 0, stream>>>(h, fin_s, fin_b, cls_w, cls_b, (float*)d_out);
}